// Round 8
// baseline (831.390 us; speedup 1.0000x reference)
//
#include <hip/hip_runtime.h>

#define B_  32
#define S_  2048
#define H_  1024
#define A_  256
#define L_  10

typedef _Float16 f16;
typedef f16   f16v8 __attribute__((ext_vector_type(8)));
typedef float f32x4 __attribute__((ext_vector_type(4)));

// ---------------------------------------------------------------------------
// pack_weights (fp16): W1 [L][H][A], W2 [L][A][H] -> MFMA B-frag order.
// slot = ln*8+i <-> k = (ln>>4)*8+i, n = nt*16 + (ln&15).
// w1p: [lid][ktg 32][nt 16][512]; w2p: [lid][kt 8][nt 64][512].
// ---------------------------------------------------------------------------
__global__ __launch_bounds__(256) void pack_weights(
    const float* __restrict__ W1, const float* __restrict__ W2,
    f16* __restrict__ w1p, f16* __restrict__ w2p)
{
    const int p = blockIdx.x;
    const int t = threadIdx.x;
    const float* src; int sstride; f16* dst; size_t dbase;
    if (p < 320) {                       // W1: (lid, ktg) -> 32k x 256n patch
        int lid = p >> 5, ktg = p & 31;
        src = W1 + ((size_t)lid * H_ + ktg * 32) * A_;
        sstride = A_;
        dst = w1p; dbase = (size_t)(lid * 32 + ktg) * 8192;
    } else {                             // W2: (lid, kt, nquarter)
        int p2 = p - 320;
        int lid = p2 >> 5, kt = (p2 >> 2) & 7, nq = p2 & 3;
        src = W2 + ((size_t)lid * A_ + kt * 32) * H_ + nq * 256;
        sstride = H_;
        dst = w2p; dbase = ((size_t)(lid * 8 + kt) * 64 + nq * 16) * 512;
    }
    const int ln = t & 63;
    const int k0 = (ln >> 4) * 8;
    const int nn = ln & 15;
    #pragma unroll
    for (int r = 0; r < 4; ++r) {
        int nt = r * 4 + (t >> 6);       // tile 0..15 within the patch
        const float* s = src + (size_t)k0 * sstride + nt * 16 + nn;
        f16v8 h8;
        #pragma unroll
        for (int i = 0; i < 8; ++i) h8[i] = (f16)s[(size_t)i * sstride];
        *(f16v8*)(dst + dbase + (size_t)nt * 512 + (size_t)ln * 8) = h8;
    }
}

// ---------------------------------------------------------------------------
// Fused, direct-B: weights stream global(L2)->VGPR as ready-made fragments
// (16B/lane coalesced). No glds16, no weight LDS, no K-loop barriers in P2.
// Block = 32 rows, 512 thr (8 waves, 2m x 4n), 2 blocks/CU (LDS 33 KB,
// VGPR<=128 via launch_bounds; 64-f32 acc2 expected in AGPRs like r7).
// P1: 8 phases of K=128; X f32->f16 staged to XOR-swizzled LDS dbuf with
// distance-2 register prefetch; B-frags direct from w1p. 1 barrier/phase.
// P2: barrier-free 8x(1 ds_read + 16 B-loads + 16 MFMA); LN epilogue.
// ---------------------------------------------------------------------------
__global__ __launch_bounds__(512, 4) void fused_adapter(
    const float* __restrict__ X, const int* __restrict__ langs,
    const float* __restrict__ b1, const float* __restrict__ b2,
    const float* __restrict__ gamma, const float* __restrict__ beta,
    const f16* __restrict__ w1p, const f16* __restrict__ w2p,
    float* __restrict__ out)
{
    __shared__ __align__(16) f16 xbuf[2][32][128];  // 16 KB, col ^ ((row&7)<<3)
    __shared__ __align__(16) f16 hh[32 * 256];      // 16 KB, col ^ ((row&7)<<3)
    __shared__ float part[32][4][2];
    __shared__ float mrstd[32][2];

    // XCD-aware decode: XCD k serves batches 4k..4k+3 (1 MB packed weights
    // per language -> L2-resident per XCD).
    const int fid = blockIdx.x;          // 2048 blocks
    const int uu  = fid >> 3;            // 0..255
    const int b   = (fid & 7) * 4 + (uu >> 6);
    const int s0  = (uu & 63) * 32;
    const int lid = langs[b];

    const int t = threadIdx.x, lane = t & 63, wid = t >> 6;
    const int wm = wid >> 2, wn = wid & 3;
    const int lr = lane & 15, lg = lane >> 4;

    const float* Xb = X + ((size_t)(b * S_ + s0)) * H_;
    const f16* w1base = w1p + (size_t)lid * 262144;
    const f16* w2base = w2p + (size_t)lid * 262144;

    // ======================= P1: h = relu(X@W1+b1) =======================
    f32x4 acc1[4];
    #pragma unroll
    for (int nf = 0; nf < 4; ++nf) acc1[nf] = f32x4{0.f, 0.f, 0.f, 0.f};

    const int srow = t >> 4, scg = (t & 15) * 8;  // staging: row, 8-col group
    const int sws  = (srow & 7) << 3;
    f16* xdst0 = &xbuf[0][srow][scg ^ sws];
    f16* xdst1 = &xbuf[1][srow][scg ^ sws];
    const float* xsrc = Xb + (size_t)srow * H_ + scg;

    float4 h0, h1;                        // held X for slice kc+1
    {   // prologue: slice 0 -> buf0; slice 1 -> regs
        float4 a0 = *(const float4*)(xsrc);
        float4 a1 = *(const float4*)(xsrc + 4);
        f16v8 v = {(f16)a0.x,(f16)a0.y,(f16)a0.z,(f16)a0.w,
                   (f16)a1.x,(f16)a1.y,(f16)a1.z,(f16)a1.w};
        *(f16v8*)xdst0 = v;
        h0 = *(const float4*)(xsrc + 128);
        h1 = *(const float4*)(xsrc + 132);
    }
    __syncthreads();

    #pragma unroll 1
    for (int kc = 0; kc < 8; ++kc) {
        float4 n0, n1;
        if (kc < 6) {                     // distance-2 X prefetch
            n0 = *(const float4*)(xsrc + (size_t)(kc + 2) * 128);
            n1 = *(const float4*)(xsrc + (size_t)(kc + 2) * 128 + 4);
        }
        const int arow = wm * 16 + lr;
        const int swa  = (arow & 7) << 3;
        #pragma unroll
        for (int kt = 0; kt < 4; ++kt) {
            f16v8 a = *(const f16v8*)&xbuf[kc & 1][arow][(kt * 32 + lg * 8) ^ swa];
            const int kg = kc * 4 + kt;
            #pragma unroll
            for (int nf = 0; nf < 4; ++nf) {
                f16v8 bb = *(const f16v8*)(w1base
                           + ((size_t)(kg * 16 + wn * 4 + nf)) * 512 + lane * 8);
                acc1[nf] = __builtin_amdgcn_mfma_f32_16x16x32_f16(a, bb, acc1[nf], 0, 0, 0);
            }
        }
        if (kc < 7) {                     // write slice kc+1 to other buffer
            f16v8 v = {(f16)h0.x,(f16)h0.y,(f16)h0.z,(f16)h0.w,
                       (f16)h1.x,(f16)h1.y,(f16)h1.z,(f16)h1.w};
            *(f16v8*)((kc & 1) ? xdst0 : xdst1) = v;
        }
        h0 = n0; h1 = n1;
        __syncthreads();
    }

    // epilogue-1: bias + relu -> swizzled h in LDS
    #pragma unroll
    for (int nf = 0; nf < 4; ++nf) {
        int k = wn * 64 + nf * 16 + lr;
        float bias = b1[lid * A_ + k];
        #pragma unroll
        for (int r = 0; r < 4; ++r) {
            int row = wm * 16 + lg * 4 + r;
            float v = acc1[nf][r] + bias;
            v = v > 0.f ? v : 0.f;
            hh[row * 256 + (k ^ ((row & 7) << 3))] = (f16)v;
        }
    }
    __syncthreads();                      // h visible to all waves

    // ======================= P2: x + h@W2 + b2 (no barriers) ===============
    f32x4 acc2[16];
    #pragma unroll
    for (int i = 0; i < 16; ++i) acc2[i] = f32x4{0.f, 0.f, 0.f, 0.f};

    {
        const int arow = wm * 16 + lr;
        const int swa  = (arow & 7) << 3;
        #pragma unroll 1
        for (int kt = 0; kt < 8; ++kt) {
            f16v8 a2 = *(const f16v8*)&hh[arow * 256 + ((kt * 32 + lg * 8) ^ swa)];
            #pragma unroll
            for (int nf = 0; nf < 16; ++nf) {
                f16v8 bb = *(const f16v8*)(w2base
                           + ((size_t)(kt * 64 + wn * 16 + nf)) * 512 + lane * 8);
                acc2[nf] = __builtin_amdgcn_mfma_f32_16x16x32_f16(a2, bb, acc2[nf], 0, 0, 0);
            }
        }
    }

    // residual (fp32 X re-read) + LN statistics
    float s1[4] = {0.f,0.f,0.f,0.f}, s2[4] = {0.f,0.f,0.f,0.f};
    #pragma unroll 4
    for (int nf = 0; nf < 16; ++nf) {
        int col = wn * 256 + nf * 16 + lr;
        float bb2 = b2[lid * H_ + col];
        #pragma unroll
        for (int r = 0; r < 4; ++r) {
            int row = wm * 16 + lg * 4 + r;
            float x = acc2[nf][r] + bb2 + Xb[(size_t)row * H_ + col];
            acc2[nf][r] = x;
            s1[r] += x; s2[r] += x * x;
        }
    }

    #pragma unroll
    for (int r = 0; r < 4; ++r) {
        float a = s1[r], c = s2[r];
        #pragma unroll
        for (int m = 1; m < 16; m <<= 1) { a += __shfl_xor(a, m); c += __shfl_xor(c, m); }
        if (lr == 0) {
            int row = wm * 16 + lg * 4 + r;
            part[row][wn][0] = a; part[row][wn][1] = c;
        }
    }
    __syncthreads();
    if (t < 32) {
        float a = part[t][0][0] + part[t][1][0] + part[t][2][0] + part[t][3][0];
        float c = part[t][0][1] + part[t][1][1] + part[t][2][1] + part[t][3][1];
        float mean = a * (1.f / 1024.f);
        float var  = c * (1.f / 1024.f) - mean * mean;
        mrstd[t][0] = mean;
        mrstd[t][1] = rsqrtf(var + 1e-5f);
    }
    __syncthreads();

    float* ob = out + ((size_t)(b * S_ + s0)) * H_;
    #pragma unroll 4
    for (int nf = 0; nf < 16; ++nf) {
        int col = wn * 256 + nf * 16 + lr;
        float g  = gamma[lid * H_ + col];
        float bt = beta[lid * H_ + col];
        #pragma unroll
        for (int r = 0; r < 4; ++r) {
            int row = wm * 16 + lg * 4 + r;
            float x = acc2[nf][r];
            ob[(size_t)row * H_ + col] = (x - mrstd[row][0]) * mrstd[row][1] * g + bt;
        }
    }
}

// ---------------------------------------------------------------------------
extern "C" void kernel_launch(void* const* d_in, const int* in_sizes, int n_in,
                              void* d_out, int out_size, void* d_ws, size_t ws_size,
                              hipStream_t stream)
{
    const float* X     = (const float*)d_in[0];
    const int*   langs = (const int*)  d_in[1];
    const float* W1    = (const float*)d_in[2];
    const float* b1    = (const float*)d_in[3];
    const float* W2    = (const float*)d_in[4];
    const float* b2    = (const float*)d_in[5];
    const float* gamma = (const float*)d_in[6];
    const float* beta  = (const float*)d_in[7];
    float* out = (float*)d_out;

    char* ws = (char*)d_ws;
    f16* w1p = (f16*)(ws);               // 5,242,880 B
    f16* w2p = (f16*)(ws + 5242880);     // 5,242,880 B  (total 10.5 MB of d_ws)

    hipLaunchKernelGGL(pack_weights, dim3(640), dim3(256), 0, stream,
                       W1, W2, w1p, w2p);
    hipLaunchKernelGGL(fused_adapter, dim3(2048), dim3(512), 0, stream,
                       X, langs, b1, b2, gamma, beta, w1p, w2p, out);
}